// Round 7
// baseline (275.573 us; speedup 1.0000x reference)
//
#include <hip/hip_runtime.h>
#include <stdint.h>

#define PR1 73856093u
#define PR2 19349663u
#define PR3 83492791u
#define PR4 2654435761u
#define GS  32      // chunks per scan group
#define PPT 4       // points per thread per turn-round in k_perm
#define BBITS 13    // bucket-id bits for ballot match (NB <= 8192)

// Branch-free uniform-divisor mod (exact for h < 2^32 via double).
__device__ __forceinline__ uint32_t fastmod(uint32_t h, uint32_t d, double inv) {
    uint32_t q = (uint32_t)((double)h * inv);
    int32_t r = (int32_t)(h - q * d);
    if (r >= (int32_t)d) r -= d;
    if (r < 0) r += d;
    return (uint32_t)r;
}

// K1: bucket per point (float out), per-chunk histogram (u16) -> ch[c][b].
__global__ void k_bucket_hist(const float* __restrict__ coords,
                              const int* __restrict__ seps, int B,
                              const int* __restrict__ hash_op_p,
                              int N, int NB, int chunk, double invNB,
                              float* __restrict__ out_bucket,
                              uint16_t* __restrict__ ch) {
    extern __shared__ int hist[];          // NB ints
    __shared__ int s_seps[1024];
    const int tid = threadIdx.x;
    for (int i = tid; i < NB; i += blockDim.x) hist[i] = 0;
    const int Bc = B < 1024 ? B : 1024;
    for (int j = tid; j < Bc; j += blockDim.x) s_seps[j] = seps[j];
    __syncthreads();

    const uint32_t hop = (uint32_t)hash_op_p[0];
    const int c = blockIdx.x;
    const int start = c * chunk;
    const int end   = min(start + chunk, N);
    int bid = 0;                            // running searchsorted-right pointer
    for (int i = start + tid; i < end; i += blockDim.x) {
        while (bid < B) {
            const int sv = (bid < 1024) ? s_seps[bid] : seps[bid];
            if (sv <= i) bid++; else break;
        }
        const float x = coords[3 * (size_t)i + 0];
        const float y = coords[3 * (size_t)i + 1];
        const float z = coords[3 * (size_t)i + 2];
        const uint32_t vx = (uint32_t)(int32_t)floorf(x);
        const uint32_t vy = (uint32_t)(int32_t)floorf(y);
        const uint32_t vz = (uint32_t)(int32_t)floorf(z);
        uint32_t h = vx * PR1 ^ vy * PR2 ^ vz * PR3 ^ ((uint32_t)bid * PR4);
        h += hop;
        const uint32_t b = fastmod(h, (uint32_t)NB, invNB);
        out_bucket[i] = (float)b;
        atomicAdd(&hist[(int)b], 1);
    }
    __syncthreads();
    uint16_t* dst = ch + (size_t)c * NB;
    for (int i = tid; i < NB; i += blockDim.x) dst[i] = (uint16_t)hist[i];
}

// K2a: per bucket, exclusive scan within each group of GS chunks, stored
// CLAMPED at 512 (u16, in place); exact group totals -> Sg[g][b] (int).
__global__ void k_scan_group(uint16_t* __restrict__ ch, int* __restrict__ Sg,
                             int C, int NB) {
    const int b = blockIdx.x * blockDim.x + threadIdx.x;
    if (b >= NB) return;
    const int g  = blockIdx.y;
    const int c0 = g * GS;
    const int c1 = min(c0 + GS, C);
    int run = 0;
    for (int c = c0; c < c1; c++) {
        const size_t idx = (size_t)c * NB + b;
        const int v = ch[idx];
        ch[idx] = (uint16_t)(run < 512 ? run : 512);
        run += v;
    }
    Sg[(size_t)g * NB + b] = run;
}

// K2b: exclusive scan over group totals (int, exact, in place); total ->
// counts (float); write -1 sentinels into perm for unfilled slots
// [min(count,512),512) — k_gather turns sentinels into zero coords.
__global__ void k_scan_tops(int* __restrict__ Sg, int G, int NB,
                            float* __restrict__ out_counts,
                            int* __restrict__ perm, int pstride) {
    const int b = blockIdx.x * blockDim.x + threadIdx.x;
    if (b >= NB) return;
    int run = 0;
    for (int g = 0; g < G; g++) {
        const size_t idx = (size_t)g * NB + b;
        const int v = Sg[idx];
        Sg[idx] = run;
        run += v;
    }
    out_counts[b] = (float)run;
    const int c0 = run < 512 ? run : 512;
    for (int j = c0; j < 512; j++)
        perm[((size_t)b * 512 + j) * pstride] = -1;
}

// K3a: stable within-bucket rank (arrival order); writes point index into
// perm[slot] (4 B) instead of scattering 12 B coords — shrinks the
// random-write footprint 3x and drops the coord reads entirely.
__global__ __launch_bounds__(256, 4)
void k_perm(const float* __restrict__ bucket_f,
            const uint16_t* __restrict__ ch,
            const int* __restrict__ Sg,
            int N, int NB, int chunk,
            int* __restrict__ perm, int pstride) {
    extern __shared__ int hist[];          // NB running counters
    const int tid = threadIdx.x;
    const int c = blockIdx.x;
    const int g = c / GS;
    const uint16_t* r1 = ch + (size_t)c * NB;
    const int*      r2 = Sg + (size_t)g * NB;
    for (int i = tid; i < NB; i += blockDim.x) hist[i] = (int)r1[i] + r2[i];
    __syncthreads();

    const int start = c * chunk;
    const int end   = min(start + chunk, N);
    const int len   = end > start ? end - start : 0;
    const int per_round = (int)blockDim.x * PPT;     // 1024
    const int rounds = (len + per_round - 1) / per_round;
    const int lane = tid & 63;
    const int wv   = tid >> 6;
    const int nw   = (int)blockDim.x >> 6;
    const unsigned long long ltmask = ((unsigned long long)1 << lane) - 1;

    for (int rd = 0; rd < rounds; rd++) {
        const int wbase = start + rd * per_round + wv * (64 * PPT);
        int bs[PPT], leader[PPT], cntv[PPT], rnk[PPT];

        #pragma unroll
        for (int s = 0; s < PPT; s++) {
            const int i = wbase + s * 64 + lane;
            bs[s] = (i < end) ? (int)bucket_f[i] : NB;   // NB sentinel fits BBITS
        }

        // Ballot multi-split: mm = mask of lanes with identical bucket id.
        #pragma unroll
        for (int s = 0; s < PPT; s++) {
            const int b = bs[s];
            unsigned long long mm = ~0ull;
            #pragma unroll
            for (int k = 0; k < BBITS; k++) {
                const unsigned long long blt = __ballot(((b >> k) & 1) != 0);
                mm &= ((b >> k) & 1) ? blt : ~blt;
            }
            leader[s] = (int)__builtin_ctzll(mm);
            cntv[s]   = (int)__builtin_popcountll(mm);
            rnk[s]    = (int)__builtin_popcountll(mm & ltmask);
        }

        // Wave turn loop: arrival order = wave 0..nw-1, sub-batch 0..PPT-1.
        int basev[PPT];
        for (int w = 0; w < nw; w++) {
            if (wv == w) {
                #pragma unroll
                for (int s = 0; s < PPT; s++) {
                    int old = 0;
                    if (bs[s] < NB && lane == leader[s])
                        old = atomicAdd(&hist[bs[s]], cntv[s]);
                    basev[s] = __shfl(old, leader[s], 64);
                }
            }
            __syncthreads();
        }

        #pragma unroll
        for (int s = 0; s < PPT; s++) {
            if (bs[s] < NB) {
                const int r = basev[s] + rnk[s];
                if (r < 512)
                    perm[((size_t)bs[s] * 512 + r) * pstride] =
                        wbase + s * 64 + lane;
            }
        }
    }
}

// K3b: slot-ordered gather. perm read + output write fully coalesced
// (write amplification 1.0); coords gather is random 12 B reads absorbed
// by the 256 MB L3 (coords = 48 MB, resident).
__global__ void k_gather(const int* __restrict__ perm, int pstride,
                         const float* __restrict__ coords,
                         int nslots, float* __restrict__ out_sc) {
    const int base = blockIdx.x * (int)blockDim.x * PPT;
    int idx[PPT];
    #pragma unroll
    for (int s = 0; s < PPT; s++) {
        const int j = base + s * (int)blockDim.x + (int)threadIdx.x;
        idx[s] = (j < nslots) ? perm[(size_t)j * pstride] : -2;
    }
    #pragma unroll
    for (int s = 0; s < PPT; s++) {
        const int j = base + s * (int)blockDim.x + (int)threadIdx.x;
        if (idx[s] == -2) continue;
        const bool v = (idx[s] >= 0);
        const float* cp = coords + 3 * (size_t)(v ? idx[s] : 0);
        const float x = v ? cp[0] : 0.f;
        const float y = v ? cp[1] : 0.f;
        const float z = v ? cp[2] : 0.f;
        float* p = out_sc + 3 * (size_t)j;
        p[0] = x; p[1] = y; p[2] = z;
    }
}

extern "C" void kernel_launch(void* const* d_in, const int* in_sizes, int n_in,
                              void* d_out, int out_size, void* d_ws, size_t ws_size,
                              hipStream_t stream) {
    const float* coords  = (const float*)d_in[0];
    const int*   seps    = (const int*)d_in[1];
    const int*   hash_op = (const int*)d_in[2];

    const int N = in_sizes[0] / 3;
    const int B = in_sizes[1];
    const int pad_to = ((N + 511) / 512) * 512;
    const int NB = pad_to / 512;

    float* out        = (float*)d_out;
    float* out_counts = out + (size_t)pad_to * 3;
    float* out_bucket = out_counts + NB;

    // Workspace layout: perm (int, pad_to) | ch (u16, C x NB) | Sg (int, G x NB).
    // If ws can't hold packed perm at C=1024, embed perm in the scattered
    // output region (stride 3, slot j at out[3j]) — k_gather overwrites it.
    const size_t permB = (((size_t)pad_to * 4) + 255) & ~(size_t)255;
    int* perm; int pstride; char* wsrest; size_t wsrem;
    if (ws_size > permB + (size_t)1024 * NB * 2 + (size_t)32 * NB * 4 + 256) {
        perm = (int*)d_ws; pstride = 1;
        wsrest = (char*)d_ws + permB; wsrem = ws_size - permB;
    } else {
        perm = (int*)out; pstride = 3;
        wsrest = (char*)d_ws; wsrem = ws_size;
    }
    int C = 1024;
    while (C > 8) {
        const int G_ = (C + GS - 1) / GS;
        if ((size_t)C * NB * 2 + (size_t)G_ * NB * 4 + 64 <= wsrem) break;
        C -= 8;
    }
    const int G = (C + GS - 1) / GS;
    const int chunk = (N + C - 1) / C;
    uint16_t* ch = (uint16_t*)wsrest;
    int* Sg = (int*)(wsrest + (((size_t)C * NB * 2 + 15) & ~(size_t)15));
    const size_t lds = (size_t)NB * sizeof(int);
    const double invNB = 1.0 / (double)NB;

    k_bucket_hist<<<C, 256, lds, stream>>>(coords, seps, B, hash_op, N, NB,
                                           chunk, invNB, out_bucket, ch);
    dim3 g2a((NB + 255) / 256, G);
    k_scan_group<<<g2a, 256, 0, stream>>>(ch, Sg, C, NB);
    k_scan_tops<<<(NB + 255) / 256, 256, 0, stream>>>(Sg, G, NB, out_counts,
                                                      perm, pstride);
    k_perm<<<C, 256, lds, stream>>>(out_bucket, ch, Sg, N, NB, chunk,
                                    perm, pstride);
    const int slots_per_blk = 256 * PPT;
    k_gather<<<(pad_to + slots_per_blk - 1) / slots_per_blk, 256, 0, stream>>>(
        perm, pstride, coords, pad_to, out);
}